// Round 16
// baseline (217.717 us; speedup 1.0000x reference)
//
#include <hip/hip_runtime.h>

#define B_ 4
#define T_ 2048
#define H_ 8
#define E_ 64
#define KDIM 512

typedef unsigned short ushort_t;
typedef __attribute__((ext_vector_type(4))) float f32x4;
typedef __attribute__((ext_vector_type(4))) int i32x4;
typedef __attribute__((ext_vector_type(8))) short s16x8;

// fold (1/64^0.25) * sqrt(log2(e)) into both Wq and Wk -> logits arrive pre-multiplied by log2(e)
#define QK_SCALE 0.42466043f

__device__ __forceinline__ ushort_t f2bf(float f) {   // RNE
  unsigned u = __builtin_bit_cast(unsigned, f);
  u += 0x7fffu + ((u >> 16) & 1u);
  return (ushort_t)(u >> 16);
}
__device__ __forceinline__ unsigned pk2(float a, float b) {  // RNE pack
  return (unsigned)f2bf(a) | ((unsigned)f2bf(b) << 16);
}
// truncating pack, single v_perm_b32: dst = {hi16(b), hi16(a)}
__device__ __forceinline__ unsigned pk2t(float a, float b) {
  return __builtin_amdgcn_perm(__builtin_bit_cast(unsigned, b),
                               __builtin_bit_cast(unsigned, a), 0x07060302u);
}
__device__ __forceinline__ float e2(float x) { return __builtin_amdgcn_exp2f(x); }
// async global->LDS, 16B per lane, LDS dest = wave-uniform base + lane*16
__device__ __forceinline__ void gl2lds16(const void* g, void* l) {
  __builtin_amdgcn_global_load_lds((const __attribute__((address_space(1))) unsigned*)g,
                                   (__attribute__((address_space(3))) unsigned*)l, 16, 0, 0);
}

// ---------------- fused preprocessing: prep + wgt + cvt in ONE launch ---------------
// (r11 structure, proven. r12 memset-fusion neutral-negative -> not used.)
__global__ void k_pre(const float* __restrict__ Wq, const float* __restrict__ Wk,
                      const float* __restrict__ Wv, const float* __restrict__ mw,
                      const float* __restrict__ obs, const float* __restrict__ st,
                      ushort_t* __restrict__ wt, float* __restrict__ wgt,
                      unsigned* __restrict__ xo, unsigned* __restrict__ xs) {
  int bid = blockIdx.x;
  if (bid < 192) {
    // ---- weight prep: LDS-tiled transpose to [N][K] bf16, fold scales ----
    __shared__ ushort_t tile[64][66];
    int z = bid >> 6;                  // 0..2  (Wq/Wk/Wv)
    int rem = bid & 63;
    int n0 = (rem & 7) << 6;
    int k0 = (rem >> 3) << 6;
    const float* W = (z == 0) ? Wq : (z == 1 ? Wk : Wv);
    float scale = (z < 2) ? QK_SCALE : 1.0f;
    int rr = threadIdx.x >> 6, cc = threadIdx.x & 63;
    for (int p = 0; p < 16; p++) {
      int kl = p * 4 + rr;
      tile[cc][kl] = f2bf(W[(size_t)(k0 + kl) * 512 + n0 + cc] * scale);
    }
    __syncthreads();
    int kp2 = threadIdx.x & 31, nr = threadIdx.x >> 5;
    unsigned* wt32 = (unsigned*)(wt + (size_t)z * 262144);
    for (int p = 0; p < 8; p++) {
      int nl = p * 8 + nr;
      unsigned val = (unsigned)tile[nl][kp2 * 2] | ((unsigned)tile[nl][kp2 * 2 + 1] << 16);
      wt32[(size_t)(n0 + nl) * 256 + (k0 >> 1) + kp2] = val;
    }
  } else if (bid == 192) {
    // ---- merge-weight softmax over heads: wgt[h][e] ----
    if (threadIdx.x < 64) {
      int e = threadIdx.x;
      float w[8], wmax = -1e30f;
      for (int h = 0; h < 8; h++) { w[h] = mw[h * 64 + e]; wmax = fmaxf(wmax, w[h]); }
      float wsum = 0.f;
      for (int h = 0; h < 8; h++) { w[h] = __expf(w[h] - wmax); wsum += w[h]; }
      float inv = 1.f / wsum;
      for (int h = 0; h < 8; h++) wgt[h * 64 + e] = w[h] * inv;
    }
  } else {
    // ---- activation fp32 -> bf16 pre-convert (streaming, RNE) ----
    int cb = bid - 193;                // 0..4095
    int which = cb >> 11;
    int inner = cb & 2047;
    const float* src = which ? st : obs;
    unsigned* dst = which ? xs : xo;
    size_t idx = (size_t)inner * 256 + threadIdx.x;
    size_t base = idx * 8;
    float4 x0 = *(const float4*)(src + base);
    float4 x1 = *(const float4*)(src + base + 4);
    uint4 d;
    d.x = pk2(x0.x, x0.y);
    d.y = pk2(x0.z, x0.w);
    d.z = pk2(x1.x, x1.y);
    d.w = pk2(x1.z, x1.w);
    *(uint4*)(dst + idx * 4) = d;
  }
}

// ---------------- QKV projection v18: 64x128 tiles @ launch_bounds(256,5) -----------
// v17 (bounds(256,4)) validated the latency-TLP theory: VGPR 64 no-spill, FETCH
// dropped to ideal 16.3 MB, WRITE to ideal 24.6 MB, 58.5 -> 54.2 us at 16 waves/CU.
// Still latency-bound (MfmaUtil 8.4%, HBM 9.6%, occ 33%) -> one more TLP notch:
// bounds(256,5) gives a 512/5=102-reg budget vs the measured 96-reg working set
// (64 arch + 32 acc); v16's spill was budget 85 < 96, this clears it. 5 blocks/CU =
// 20 waves/CU. Body/grid/ladder identical to the twice-proven v17.
__global__ __launch_bounds__(256, 5) void k_proj2(
    const ushort_t* __restrict__ xo, const ushort_t* __restrict__ xs,
    const ushort_t* __restrict__ wt,
    ushort_t* __restrict__ qo, ushort_t* __restrict__ ko, ushort_t* __restrict__ vto) {
  __shared__ __align__(16) ushort_t As[3][64 * 64];   // 24 KB, 5 blocks/CU = 120 KB

  int id = blockIdx.x;              // 1536
  int xcd = id & 7, nt = (id >> 3) & 3, ghi = id >> 5;
  int g = ghi * 8 + xcd;            // [0,384); 4 n-tiles of one m-block share an XCD
  int which = g >> 7, mb = g & 127;
  int m0 = mb << 6, n0 = nt << 7;
  const ushort_t* X = (which == 0) ? xo : xs;
  const ushort_t* W = wt + which * 262144;

  int tid = threadIdx.x, wave = tid >> 6, lane = tid & 63;
  int l15 = lane & 15, quad = lane >> 4;
  int wm = wave & 1, wn = wave >> 1;

  f32x4 acc[2][4];
  for (int i = 0; i < 2; i++)
    for (int j = 0; j < 4; j++) acc[i][j] = (f32x4){0.f, 0.f, 0.f, 0.f};

  int arl = lane >> 3, ap = lane & 7;  // A stage: 8 rows/instr, 8 chunks(16B)/row

#define STAGEA(buf, k0)                                                            \
  do {                                                                             \
    for (int ii = 0; ii < 2; ii++) {                                               \
      int r = wave * 16 + ii * 8 + arl;                                            \
      gl2lds16(X + (size_t)(m0 + r) * KDIM + (k0) + ((ap ^ (r & 7)) << 3),         \
               &As[buf][(wave * 16 + ii * 8) * 64]);                               \
    }                                                                              \
  } while (0)

  // B row pointers (advance by 64 per k-iter)
  const ushort_t* wb[4];
  for (int j = 0; j < 4; j++)
    wb[j] = W + (size_t)(n0 + wn * 64 + j * 16 + l15) * KDIM + quad * 8;

  STAGEA(0, 0);                        // st0 (2 ops/wave)
  STAGEA(1, 64);                       // st1 (2 ops/wave)
  __builtin_amdgcn_s_waitcnt(0x0F72);  // vmcnt(2): st0 landed, st1 in flight
  __builtin_amdgcn_s_barrier();
  __builtin_amdgcn_sched_barrier(0);

#pragma unroll
  for (int kt = 0; kt < 8; kt++) {
    // 1) B[kt] register loads FIRST (8 ops)
    s16x8 b[2][4];
    for (int kc = 0; kc < 2; kc++)
      for (int j = 0; j < 4; j++) b[kc][j] = *(const s16x8*)(wb[j] + kc * 32);
    for (int j = 0; j < 4; j++) wb[j] += 64;
    // 2) stage tile kt+2 (2 ops); its readers ran at iter kt-1, behind that barrier
    if (kt < 6) STAGEA((kt + 2) % 3, (kt + 2) * 64);
    // 3) counted wait: retire {st kt+1, B[kt]}; keep st kt+2 in flight
    if (kt < 6) __builtin_amdgcn_s_waitcnt(0x0F72);   // vmcnt(2)
    else        __builtin_amdgcn_s_waitcnt(0x0F70);   // tail: vmcnt(0)
    __builtin_amdgcn_sched_barrier(0);
    // 4) compute current tile (pure b128 LDS reads, no conversion)
    const ushort_t* asb = As[kt % 3];
    for (int kc = 0; kc < 2; kc++) {
      s16x8 a[2];
      for (int i = 0; i < 2; i++) {
        int mr = wm * 32 + i * 16 + l15;
        int pc = (kc * 4 + quad) ^ (l15 & 7);
        a[i] = *(const s16x8*)&asb[mr * 64 + pc * 8];
      }
      if (which == 2) {
        for (int i = 0; i < 2; i++)
          for (int j = 0; j < 4; j++)
            acc[i][j] = __builtin_amdgcn_mfma_f32_16x16x32_bf16(b[kc][j], a[i], acc[i][j], 0, 0, 0);
      } else {
        for (int i = 0; i < 2; i++)
          for (int j = 0; j < 4; j++)
            acc[i][j] = __builtin_amdgcn_mfma_f32_16x16x32_bf16(a[i], b[kc][j], acc[i][j], 0, 0, 0);
      }
    }
    if (kt < 7) {
      __builtin_amdgcn_s_barrier();    // raw barrier: no implicit vmcnt(0) drain
      __builtin_amdgcn_sched_barrier(0);
    }
  }
#undef STAGEA

  // ---- epilogue: stores grouped per 128B line ----
  if (which != 2) {
    ushort_t* dst = (which == 0) ? qo : ko;
    int h = (n0 >> 6) + wn;            // e = j*16 + l15 (n0, wn*64 are 64-aligned)
    for (int i = 0; i < 2; i++) {
      for (int r = 0; r < 4; r++) {
        int row = m0 + wm * 32 + i * 16 + quad * 4 + r;
        int bb = row >> 11, t = row & 2047;
        size_t lbase = (((size_t)(bb * H_ + h) * T_ + t) << 6);
        for (int j = 0; j < 4; j++) {   // 4 stores = one full 128B line
          int e = j * 16 + l15;
          dst[lbase + e] = f2bf(acc[i][j][r]);
        }
      }
    }
  } else {
    for (int j = 0; j < 4; j++) {
      for (int r = 0; r < 4; r++) {
        int gcol = n0 + wn * 64 + j * 16 + quad * 4 + r;
        int h = gcol >> 6, e = gcol & 63;
        size_t lbase = ((size_t)(((m0 >> 11) * H_ + h) << 6) + e) * T_;
        for (int i = 0; i < 2; i++) {
          int t = (m0 & 2047) + wm * 32 + i * 16 + l15;
          vto[lbase + t] = f2bf(acc[i][j][r]);
        }
      }
    }
  }
}

// ---------------- QKV projection v7 (fp32 fallback, proven) -------------------------
__global__ __launch_bounds__(256, 3) void k_proj(
    const float* __restrict__ obs, const float* __restrict__ st,
    const ushort_t* __restrict__ wt,
    ushort_t* __restrict__ qo, ushort_t* __restrict__ ko, ushort_t* __restrict__ vto) {
  __shared__ __align__(16) float As[2][128 * 32];   // 2 x 16 KB

  int id = blockIdx.x;              // 768
  int xcd = id & 7, nt = (id >> 3) & 3, ghi = id >> 5;
  int g = ghi * 8 + xcd;
  int which = g >> 6, mb = g & 63;
  int m0 = mb << 7, n0 = nt << 7;
  const float* X = (which == 0) ? obs : st;
  const ushort_t* W = wt + which * 262144;

  int tid = threadIdx.x, wave = tid >> 6, lane = tid & 63;
  int l15 = lane & 15, quad = lane >> 4;
  int wm = wave & 1, wn = wave >> 1;

  f32x4 acc[4][4];
  for (int i = 0; i < 4; i++)
    for (int j = 0; j < 4; j++) acc[i][j] = (f32x4){0.f, 0.f, 0.f, 0.f};

  int arl = lane >> 3, ap = lane & 7;

#define STAGEA(buf, k0)                                                           \
  do {                                                                            \
    for (int ii = 0; ii < 4; ii++) {                                              \
      int r = wave * 32 + ii * 8 + arl;                                           \
      gl2lds16(X + (size_t)(m0 + r) * KDIM + (k0) + ((ap ^ (r & 7)) << 2),        \
               &As[buf][(wave * 32 + ii * 8) * 32]);                              \
    }                                                                             \
  } while (0)

  const ushort_t* wb[4];
  for (int j = 0; j < 4; j++)
    wb[j] = W + (size_t)(n0 + wn * 64 + j * 16 + l15) * KDIM + quad * 8;

  STAGEA(0, 0);
  __builtin_amdgcn_s_waitcnt(0x0F70);
  __syncthreads();

  for (int kt = 0; kt < 16; kt++) {
    s16x8 b[4];
    for (int j = 0; j < 4; j++) { b[j] = *(const s16x8*)wb[j]; wb[j] += 32; }
    if (kt < 15) STAGEA((kt + 1) & 1, kt * 32 + 32);
    const float* asb = As[kt & 1];
    s16x8 a[4];
    for (int i = 0; i < 4; i++) {
      int mr = wm * 64 + i * 16 + l15;
      int s = mr & 7;
      const float* rowp = &asb[mr * 32];
      float4 x0 = *(const float4*)&rowp[(((quad << 1)) ^ s) << 2];
      float4 x1 = *(const float4*)&rowp[(((quad << 1) | 1) ^ s) << 2];
      i32x4 d;
      d[0] = (int)pk2(x0.x, x0.y);
      d[1] = (int)pk2(x0.z, x0.w);
      d[2] = (int)pk2(x1.x, x1.y);
      d[3] = (int)pk2(x1.z, x1.w);
      a[i] = __builtin_bit_cast(s16x8, d);
    }
    if (which == 2) {
      for (int i = 0; i < 4; i++)
        for (int j = 0; j < 4; j++)
          acc[i][j] = __builtin_amdgcn_mfma_f32_16x16x32_bf16(b[j], a[i], acc[i][j], 0, 0, 0);
    } else {
      for (int i = 0; i < 4; i++)
        for (int j = 0; j < 4; j++)
          acc[i][j] = __builtin_amdgcn_mfma_f32_16x16x32_bf16(a[i], b[j], acc[i][j], 0, 0, 0);
    }
    __builtin_amdgcn_s_waitcnt(0x0F70);
    __syncthreads();
  }
#undef STAGEA

  if (which != 2) {
    ushort_t* dst = (which == 0) ? qo : ko;
    for (int i = 0; i < 4; i++) {
      int grow = m0 + wm * 64 + i * 16 + quad * 4;
      for (int j = 0; j < 4; j++) {
        int gcol = n0 + wn * 64 + j * 16 + l15;
        int h = gcol >> 6, e = gcol & 63;
        for (int r = 0; r < 4; r++) {
          int row = grow + r;
          int bb = row >> 11, t = row & 2047;
          int bh = bb * H_ + h;
          dst[(((size_t)bh * T_ + t) << 6) + e] = f2bf(acc[i][j][r]);
        }
      }
    }
  } else {
    for (int i = 0; i < 4; i++) {
      int row = m0 + wm * 64 + i * 16 + l15;
      int bb = row >> 11, t = row & 2047;
      for (int j = 0; j < 4; j++) {
        for (int r = 0; r < 4; r++) {
          int gcol = n0 + wn * 64 + j * 16 + quad * 4 + r;
          int h = gcol >> 6, e = gcol & 63;
          int bh = bb * H_ + h;
          vto[((size_t)(bh << 6) + e) * T_ + t] = f2bf(acc[i][j][r]);
        }
      }
    }
  }
}

// ---------------- flash attention v10 (proven ~55 us): 2-deep 32 KB LDS, 4/CU -------
// r13: direct-from-L2 V falsified (2.4x regression); LDS staging is the latency-hiding
// mechanism. Kept verbatim.
union AttnSmem {
  struct { ushort_t ks[2][64 * 64]; ushort_t vs[2][64 * 64]; } st;  // 32 KB
  struct { float ows[64 * 65]; float linv[64]; } ep;                // 16.9 KB
};

__global__ __launch_bounds__(256, 4) void k_attn(
    const ushort_t* __restrict__ q, const ushort_t* __restrict__ k,
    const ushort_t* __restrict__ vt, const float* __restrict__ wgt,
    float* __restrict__ out) {
  __shared__ __align__(16) AttnSmem sm;

  int id = blockIdx.x;      // 1024; bh fastest -> 4 heads/XCD (K+V L2-resident)
  int bh = id & 31, qt = id >> 5;   // qt in [0,32), 64 queries each
  int tid = threadIdx.x, wave = tid >> 6, lane = tid & 63;
  int l15 = lane & 15, quad = lane >> 4;

  s16x8 qf[2];              // 16 q-rows per wave
  {
    const ushort_t* qp =
        q + (((size_t)bh * T_ + qt * 64 + wave * 16 + l15) << 6) + quad * 8;
    qf[0] = *(const s16x8*)qp;
    qf[1] = *(const s16x8*)(qp + 32);
  }
  int hh = bh & 7;
  float wgl = wgt[hh * 64 + lane];

  f32x4 o[4];
  for (int j = 0; j < 4; j++) o[j] = (f32x4){0.f, 0.f, 0.f, 0.f};
  f32x4 lacc = (f32x4){0.f, 0.f, 0.f, 0.f};
  const s16x8 ones = {16256, 16256, 16256, 16256, 16256, 16256, 16256, 16256};  // bf16 1.0

  int srl = lane >> 3, sp = lane & 7;
  const ushort_t* kbase = k + ((size_t)bh * T_ << 6);
  const ushort_t* vbase = vt + ((size_t)bh << 6) * T_;
  const ushort_t* kptr[2];
  const ushort_t* vptr[2];
  for (int ii = 0; ii < 2; ii++) {
    int r = wave * 16 + ii * 8 + srl;
    int gkey = (r & 32) + (((r >> 2) & 3) << 3) + (((r >> 4) & 1) << 2) + (r & 3);
    kptr[ii] = kbase + ((size_t)gkey << 6) + ((sp ^ (r & 7)) << 3);
    int e = r;
    vptr[ii] = vbase + (size_t)e * T_ + ((sp ^ (e & 7)) << 3);
  }

#define STAGE(buf)                                                         \
  do {                                                                     \
    for (int ii = 0; ii < 2; ii++) {                                       \
      gl2lds16(kptr[ii], &sm.st.ks[buf][(wave * 16 + ii * 8) * 64]);       \
      gl2lds16(vptr[ii], &sm.st.vs[buf][(wave * 16 + ii * 8) * 64]);       \
      kptr[ii] += 64 * 64;                                                 \
      vptr[ii] += 64;                                                      \
    }                                                                      \
  } while (0)

  STAGE(0);                            // tile 0 (4 ops/wave)
  __builtin_amdgcn_s_waitcnt(0x0F70);  // vmcnt(0): tile 0 landed
  __builtin_amdgcn_s_barrier();
  __builtin_amdgcn_sched_barrier(0);

  for (int kt = 0; kt < 32; kt++) {
    // stage tile kt+1 into the other buffer; its readers ran in iter kt-1 (barrier'd)
    if (kt < 31) STAGE((kt + 1) & 1);
    const ushort_t* ksb = &sm.st.ks[0][0] + (kt & 1) * 4096;
    const ushort_t* vsb = &sm.st.vs[0][0] + (kt & 1) * 4096;

    __builtin_amdgcn_s_setprio(1);     // favor compute-phase waves (T5)
    s16x8 bfr[2];
    for (int c = 0; c < 2; c++) {
      f32x4 s0 = (f32x4){0.f, 0.f, 0.f, 0.f};
      f32x4 s1 = (f32x4){0.f, 0.f, 0.f, 0.f};
      for (int kc = 0; kc < 2; kc++) {
        int pc = (kc * 4 + quad) ^ (l15 & 7);
        s16x8 k0f = *(const s16x8*)&ksb[(c * 32 + l15) * 64 + pc * 8];
        s16x8 k1f = *(const s16x8*)&ksb[(c * 32 + 16 + l15) * 64 + pc * 8];
        s0 = __builtin_amdgcn_mfma_f32_16x16x32_bf16(k0f, qf[kc], s0, 0, 0, 0);
        s1 = __builtin_amdgcn_mfma_f32_16x16x32_bf16(k1f, qf[kc], s1, 0, 0, 0);
      }
      i32x4 d;
      d[0] = (int)pk2t(e2(s0[0]), e2(s0[1]));
      d[1] = (int)pk2t(e2(s0[2]), e2(s0[3]));
      d[2] = (int)pk2t(e2(s1[0]), e2(s1[1]));
      d[3] = (int)pk2t(e2(s1[2]), e2(s1[3]));
      bfr[c] = __builtin_bit_cast(s16x8, d);
    }

    for (int c = 0; c < 2; c++) {
      lacc = __builtin_amdgcn_mfma_f32_16x16x32_bf16(ones, bfr[c], lacc, 0, 0, 0);
      for (int et = 0; et < 4; et++) {
        int pc = (c * 4 + quad) ^ (l15 & 7);
        s16x8 vf = *(const s16x8*)&vsb[(et * 16 + l15) * 64 + pc * 8];
        o[et] = __builtin_amdgcn_mfma_f32_16x16x32_bf16(vf, bfr[c], o[et], 0, 0, 0);
      }
    }
    __builtin_amdgcn_s_setprio(0);

    // wait for tile kt+1 (issued before compute kt -> one full compute-phase in
    // flight, cheap wait); barrier so all reads of buf kt are done before iter
    // kt+1 stages into it.
    if (kt < 31) {
      __builtin_amdgcn_s_waitcnt(0x0F70);  // vmcnt(0)
      __builtin_amdgcn_s_barrier();
      __builtin_amdgcn_sched_barrier(0);
    }
  }
#undef STAGE

  int bb = bh >> 3;
  __syncthreads();   // all waves done reading ks/vs before ows overlays them
  {
    int row0 = wave * 16;
    if (quad == 0) sm.ep.linv[row0 + l15] = 1.f / lacc[0];
    for (int et = 0; et < 4; et++)
      for (int r = 0; r < 4; r++)
        sm.ep.ows[(row0 + l15) * 65 + et * 16 + quad * 4 + r] = o[et][r];
    // each wave reads back only its own 16 rows: no barrier needed
    for (int i = 0; i < 16; i++) {
      int row = row0 + i;
      int gt = qt * 64 + row;
      float val = sm.ep.ows[row * 65 + lane] * sm.ep.linv[row] * wgl;
      atomicAdd(&out[(((size_t)bb * T_ + gt) << 6) + lane], val);
    }
  }
}

extern "C" void kernel_launch(void* const* d_in, const int* in_sizes, int n_in,
                              void* d_out, int out_size, void* d_ws, size_t ws_size,
                              hipStream_t stream) {
  const float* obs = (const float*)d_in[0];
  const float* st  = (const float*)d_in[1];
  const float* Wq  = (const float*)d_in[2];
  const float* Wk  = (const float*)d_in[3];
  const float* Wv  = (const float*)d_in[4];
  const float* mw  = (const float*)d_in[5];

  const size_t WS_NEEDED = 27262976;   // proven 26 MB layout
  const size_t WS_BIG    = 44040192;   // +16 MB bf16 activations
  char* ws = (char*)d_ws;
  ushort_t* wt  = (ushort_t*)ws;                     // 1.5 MB
  float*    wgt = (float*)(ws + 1572864u);           // 2 KB
  ushort_t* qo  = (ushort_t*)(ws + 2097152u);        // [B,H,T,E] bf16, 8 MB
  ushort_t* ko  = (ushort_t*)(ws + 10485760u);       // [B,H,T,E] bf16, 8 MB
  ushort_t* vto = (ushort_t*)(ws + 18874368u);       // [B,H,E,T] bf16, 8 MB
  ushort_t* xo  = (ushort_t*)(ws + 27262976u);       // obs bf16, 8 MB
  ushort_t* xs  = (ushort_t*)(ws + 35651584u);       // st  bf16, 8 MB
  float*    out = (float*)d_out;

  hipMemsetAsync(d_out, 0, (size_t)out_size * sizeof(float), stream);
  if (ws_size < WS_NEEDED) return;

  int big = (ws_size >= WS_BIG);
  int preBlocks = big ? (193 + 4096) : 193;   // cvt section only with big workspace
  hipLaunchKernelGGL(k_pre, dim3(preBlocks), dim3(256), 0, stream,
                     Wq, Wk, Wv, mw, obs, st, wt, wgt, (unsigned*)xo, (unsigned*)xs);
  if (big) {
    hipLaunchKernelGGL(k_proj2, dim3(1536), dim3(256), 0, stream, xo, xs, wt, qo, ko, vto);
  } else {
    hipLaunchKernelGGL(k_proj,  dim3(768),  dim3(256), 0, stream, obs, st, wt, qo, ko, vto);
  }
  hipLaunchKernelGGL(k_attn, dim3(1024), dim3(256), 0, stream, qo, ko, vto, wgt, out);
}

// Round 17
// 177.117 us; speedup vs baseline: 1.2292x; 1.2292x over previous
//
#include <hip/hip_runtime.h>

#define B_ 4
#define T_ 2048
#define H_ 8
#define E_ 64
#define KDIM 512

typedef unsigned short ushort_t;
typedef __attribute__((ext_vector_type(4))) float f32x4;
typedef __attribute__((ext_vector_type(4))) int i32x4;
typedef __attribute__((ext_vector_type(8))) short s16x8;

// fold (1/64^0.25) * sqrt(log2(e)) into both Wq and Wk -> logits arrive pre-multiplied by log2(e)
#define QK_SCALE 0.42466043f

__device__ __forceinline__ ushort_t f2bf(float f) {   // RNE
  unsigned u = __builtin_bit_cast(unsigned, f);
  u += 0x7fffu + ((u >> 16) & 1u);
  return (ushort_t)(u >> 16);
}
__device__ __forceinline__ unsigned pk2(float a, float b) {  // RNE pack
  return (unsigned)f2bf(a) | ((unsigned)f2bf(b) << 16);
}
// truncating pack, single v_perm_b32: dst = {hi16(b), hi16(a)}
__device__ __forceinline__ unsigned pk2t(float a, float b) {
  return __builtin_amdgcn_perm(__builtin_bit_cast(unsigned, b),
                               __builtin_bit_cast(unsigned, a), 0x07060302u);
}
__device__ __forceinline__ float e2(float x) { return __builtin_amdgcn_exp2f(x); }
// async global->LDS, 16B per lane, LDS dest = wave-uniform base + lane*16
__device__ __forceinline__ void gl2lds16(const void* g, void* l) {
  __builtin_amdgcn_global_load_lds((const __attribute__((address_space(1))) unsigned*)g,
                                   (__attribute__((address_space(3))) unsigned*)l, 16, 0, 0);
}

// ---------------- fused preprocessing: prep + wgt + cvt in ONE launch ---------------
// (r11 structure, proven. r12 memset-fusion neutral-negative -> not used.)
__global__ void k_pre(const float* __restrict__ Wq, const float* __restrict__ Wk,
                      const float* __restrict__ Wv, const float* __restrict__ mw,
                      const float* __restrict__ obs, const float* __restrict__ st,
                      ushort_t* __restrict__ wt, float* __restrict__ wgt,
                      unsigned* __restrict__ xo, unsigned* __restrict__ xs) {
  int bid = blockIdx.x;
  if (bid < 192) {
    // ---- weight prep: LDS-tiled transpose to [N][K] bf16, fold scales ----
    __shared__ ushort_t tile[64][66];
    int z = bid >> 6;                  // 0..2  (Wq/Wk/Wv)
    int rem = bid & 63;
    int n0 = (rem & 7) << 6;
    int k0 = (rem >> 3) << 6;
    const float* W = (z == 0) ? Wq : (z == 1 ? Wk : Wv);
    float scale = (z < 2) ? QK_SCALE : 1.0f;
    int rr = threadIdx.x >> 6, cc = threadIdx.x & 63;
    for (int p = 0; p < 16; p++) {
      int kl = p * 4 + rr;
      tile[cc][kl] = f2bf(W[(size_t)(k0 + kl) * 512 + n0 + cc] * scale);
    }
    __syncthreads();
    int kp2 = threadIdx.x & 31, nr = threadIdx.x >> 5;
    unsigned* wt32 = (unsigned*)(wt + (size_t)z * 262144);
    for (int p = 0; p < 8; p++) {
      int nl = p * 8 + nr;
      unsigned val = (unsigned)tile[nl][kp2 * 2] | ((unsigned)tile[nl][kp2 * 2 + 1] << 16);
      wt32[(size_t)(n0 + nl) * 256 + (k0 >> 1) + kp2] = val;
    }
  } else if (bid == 192) {
    // ---- merge-weight softmax over heads: wgt[h][e] ----
    if (threadIdx.x < 64) {
      int e = threadIdx.x;
      float w[8], wmax = -1e30f;
      for (int h = 0; h < 8; h++) { w[h] = mw[h * 64 + e]; wmax = fmaxf(wmax, w[h]); }
      float wsum = 0.f;
      for (int h = 0; h < 8; h++) { w[h] = __expf(w[h] - wmax); wsum += w[h]; }
      float inv = 1.f / wsum;
      for (int h = 0; h < 8; h++) wgt[h * 64 + e] = w[h] * inv;
    }
  } else {
    // ---- activation fp32 -> bf16 pre-convert (streaming, RNE) ----
    int cb = bid - 193;                // 0..4095
    int which = cb >> 11;
    int inner = cb & 2047;
    const float* src = which ? st : obs;
    unsigned* dst = which ? xs : xo;
    size_t idx = (size_t)inner * 256 + threadIdx.x;
    size_t base = idx * 8;
    float4 x0 = *(const float4*)(src + base);
    float4 x1 = *(const float4*)(src + base + 4);
    uint4 d;
    d.x = pk2(x0.x, x0.y);
    d.y = pk2(x0.z, x0.w);
    d.z = pk2(x1.x, x1.y);
    d.w = pk2(x1.z, x1.w);
    *(uint4*)(dst + idx * 4) = d;
  }
}

// ---------------- QKV projection v17 (FINAL, proven 54.2 us): 64x128 @ bounds(256,4)
// r16 post-mortem: bounds(256,5) spilled (VGPR 48, FETCH 74 MB, 100 us) — the HW
// register-allocation quantum makes 5 blocks/CU unreachable for this 96-reg working
// set. The occupancy ladder is quantized: 4 blocks/CU is the stable maximum.
// v17 validated twice (r10 body correctness, r15 perf): VGPR 64 no-spill, FETCH at
// ideal 16.3 MB, WRITE at ideal 24.6 MB, 16 waves/CU, 54.2 us.
__global__ __launch_bounds__(256, 4) void k_proj2(
    const ushort_t* __restrict__ xo, const ushort_t* __restrict__ xs,
    const ushort_t* __restrict__ wt,
    ushort_t* __restrict__ qo, ushort_t* __restrict__ ko, ushort_t* __restrict__ vto) {
  __shared__ __align__(16) ushort_t As[3][64 * 64];   // 24 KB, 4 blocks/CU

  int id = blockIdx.x;              // 1536
  int xcd = id & 7, nt = (id >> 3) & 3, ghi = id >> 5;
  int g = ghi * 8 + xcd;            // [0,384); 4 n-tiles of one m-block share an XCD
  int which = g >> 7, mb = g & 127;
  int m0 = mb << 6, n0 = nt << 7;
  const ushort_t* X = (which == 0) ? xo : xs;
  const ushort_t* W = wt + which * 262144;

  int tid = threadIdx.x, wave = tid >> 6, lane = tid & 63;
  int l15 = lane & 15, quad = lane >> 4;
  int wm = wave & 1, wn = wave >> 1;

  f32x4 acc[2][4];
  for (int i = 0; i < 2; i++)
    for (int j = 0; j < 4; j++) acc[i][j] = (f32x4){0.f, 0.f, 0.f, 0.f};

  int arl = lane >> 3, ap = lane & 7;  // A stage: 8 rows/instr, 8 chunks(16B)/row

#define STAGEA(buf, k0)                                                            \
  do {                                                                             \
    for (int ii = 0; ii < 2; ii++) {                                               \
      int r = wave * 16 + ii * 8 + arl;                                            \
      gl2lds16(X + (size_t)(m0 + r) * KDIM + (k0) + ((ap ^ (r & 7)) << 3),         \
               &As[buf][(wave * 16 + ii * 8) * 64]);                               \
    }                                                                              \
  } while (0)

  // B row pointers (advance by 64 per k-iter)
  const ushort_t* wb[4];
  for (int j = 0; j < 4; j++)
    wb[j] = W + (size_t)(n0 + wn * 64 + j * 16 + l15) * KDIM + quad * 8;

  STAGEA(0, 0);                        // st0 (2 ops/wave)
  STAGEA(1, 64);                       // st1 (2 ops/wave)
  __builtin_amdgcn_s_waitcnt(0x0F72);  // vmcnt(2): st0 landed, st1 in flight
  __builtin_amdgcn_s_barrier();
  __builtin_amdgcn_sched_barrier(0);

#pragma unroll
  for (int kt = 0; kt < 8; kt++) {
    // 1) B[kt] register loads FIRST (8 ops)
    s16x8 b[2][4];
    for (int kc = 0; kc < 2; kc++)
      for (int j = 0; j < 4; j++) b[kc][j] = *(const s16x8*)(wb[j] + kc * 32);
    for (int j = 0; j < 4; j++) wb[j] += 64;
    // 2) stage tile kt+2 (2 ops); its readers ran at iter kt-1, behind that barrier
    if (kt < 6) STAGEA((kt + 2) % 3, (kt + 2) * 64);
    // 3) counted wait: retire {st kt+1, B[kt]}; keep st kt+2 in flight
    if (kt < 6) __builtin_amdgcn_s_waitcnt(0x0F72);   // vmcnt(2)
    else        __builtin_amdgcn_s_waitcnt(0x0F70);   // tail: vmcnt(0)
    __builtin_amdgcn_sched_barrier(0);
    // 4) compute current tile (pure b128 LDS reads, no conversion)
    const ushort_t* asb = As[kt % 3];
    for (int kc = 0; kc < 2; kc++) {
      s16x8 a[2];
      for (int i = 0; i < 2; i++) {
        int mr = wm * 32 + i * 16 + l15;
        int pc = (kc * 4 + quad) ^ (l15 & 7);
        a[i] = *(const s16x8*)&asb[mr * 64 + pc * 8];
      }
      if (which == 2) {
        for (int i = 0; i < 2; i++)
          for (int j = 0; j < 4; j++)
            acc[i][j] = __builtin_amdgcn_mfma_f32_16x16x32_bf16(b[kc][j], a[i], acc[i][j], 0, 0, 0);
      } else {
        for (int i = 0; i < 2; i++)
          for (int j = 0; j < 4; j++)
            acc[i][j] = __builtin_amdgcn_mfma_f32_16x16x32_bf16(a[i], b[kc][j], acc[i][j], 0, 0, 0);
      }
    }
    if (kt < 7) {
      __builtin_amdgcn_s_barrier();    // raw barrier: no implicit vmcnt(0) drain
      __builtin_amdgcn_sched_barrier(0);
    }
  }
#undef STAGEA

  // ---- epilogue: stores grouped per 128B line ----
  if (which != 2) {
    ushort_t* dst = (which == 0) ? qo : ko;
    int h = (n0 >> 6) + wn;            // e = j*16 + l15 (n0, wn*64 are 64-aligned)
    for (int i = 0; i < 2; i++) {
      for (int r = 0; r < 4; r++) {
        int row = m0 + wm * 32 + i * 16 + quad * 4 + r;
        int bb = row >> 11, t = row & 2047;
        size_t lbase = (((size_t)(bb * H_ + h) * T_ + t) << 6);
        for (int j = 0; j < 4; j++) {   // 4 stores = one full 128B line
          int e = j * 16 + l15;
          dst[lbase + e] = f2bf(acc[i][j][r]);
        }
      }
    }
  } else {
    for (int j = 0; j < 4; j++) {
      for (int r = 0; r < 4; r++) {
        int gcol = n0 + wn * 64 + j * 16 + quad * 4 + r;
        int h = gcol >> 6, e = gcol & 63;
        size_t lbase = ((size_t)(((m0 >> 11) * H_ + h) << 6) + e) * T_;
        for (int i = 0; i < 2; i++) {
          int t = (m0 & 2047) + wm * 32 + i * 16 + l15;
          vto[lbase + t] = f2bf(acc[i][j][r]);
        }
      }
    }
  }
}

// ---------------- QKV projection v7 (fp32 fallback, proven) -------------------------
__global__ __launch_bounds__(256, 3) void k_proj(
    const float* __restrict__ obs, const float* __restrict__ st,
    const ushort_t* __restrict__ wt,
    ushort_t* __restrict__ qo, ushort_t* __restrict__ ko, ushort_t* __restrict__ vto) {
  __shared__ __align__(16) float As[2][128 * 32];   // 2 x 16 KB

  int id = blockIdx.x;              // 768
  int xcd = id & 7, nt = (id >> 3) & 3, ghi = id >> 5;
  int g = ghi * 8 + xcd;
  int which = g >> 6, mb = g & 63;
  int m0 = mb << 7, n0 = nt << 7;
  const float* X = (which == 0) ? obs : st;
  const ushort_t* W = wt + which * 262144;

  int tid = threadIdx.x, wave = tid >> 6, lane = tid & 63;
  int l15 = lane & 15, quad = lane >> 4;
  int wm = wave & 1, wn = wave >> 1;

  f32x4 acc[4][4];
  for (int i = 0; i < 4; i++)
    for (int j = 0; j < 4; j++) acc[i][j] = (f32x4){0.f, 0.f, 0.f, 0.f};

  int arl = lane >> 3, ap = lane & 7;

#define STAGEA(buf, k0)                                                           \
  do {                                                                            \
    for (int ii = 0; ii < 4; ii++) {                                              \
      int r = wave * 32 + ii * 8 + arl;                                           \
      gl2lds16(X + (size_t)(m0 + r) * KDIM + (k0) + ((ap ^ (r & 7)) << 2),        \
               &As[buf][(wave * 32 + ii * 8) * 32]);                              \
    }                                                                             \
  } while (0)

  const ushort_t* wb[4];
  for (int j = 0; j < 4; j++)
    wb[j] = W + (size_t)(n0 + wn * 64 + j * 16 + l15) * KDIM + quad * 8;

  STAGEA(0, 0);
  __builtin_amdgcn_s_waitcnt(0x0F70);
  __syncthreads();

  for (int kt = 0; kt < 16; kt++) {
    s16x8 b[4];
    for (int j = 0; j < 4; j++) { b[j] = *(const s16x8*)wb[j]; wb[j] += 32; }
    if (kt < 15) STAGEA((kt + 1) & 1, kt * 32 + 32);
    const float* asb = As[kt & 1];
    s16x8 a[4];
    for (int i = 0; i < 4; i++) {
      int mr = wm * 64 + i * 16 + l15;
      int s = mr & 7;
      const float* rowp = &asb[mr * 32];
      float4 x0 = *(const float4*)&rowp[(((quad << 1)) ^ s) << 2];
      float4 x1 = *(const float4*)&rowp[(((quad << 1) | 1) ^ s) << 2];
      i32x4 d;
      d[0] = (int)pk2(x0.x, x0.y);
      d[1] = (int)pk2(x0.z, x0.w);
      d[2] = (int)pk2(x1.x, x1.y);
      d[3] = (int)pk2(x1.z, x1.w);
      a[i] = __builtin_bit_cast(s16x8, d);
    }
    if (which == 2) {
      for (int i = 0; i < 4; i++)
        for (int j = 0; j < 4; j++)
          acc[i][j] = __builtin_amdgcn_mfma_f32_16x16x32_bf16(b[j], a[i], acc[i][j], 0, 0, 0);
    } else {
      for (int i = 0; i < 4; i++)
        for (int j = 0; j < 4; j++)
          acc[i][j] = __builtin_amdgcn_mfma_f32_16x16x32_bf16(a[i], b[j], acc[i][j], 0, 0, 0);
    }
    __builtin_amdgcn_s_waitcnt(0x0F70);
    __syncthreads();
  }
#undef STAGEA

  if (which != 2) {
    ushort_t* dst = (which == 0) ? qo : ko;
    for (int i = 0; i < 4; i++) {
      int grow = m0 + wm * 64 + i * 16 + quad * 4;
      for (int j = 0; j < 4; j++) {
        int gcol = n0 + wn * 64 + j * 16 + l15;
        int h = gcol >> 6, e = gcol & 63;
        for (int r = 0; r < 4; r++) {
          int row = grow + r;
          int bb = row >> 11, t = row & 2047;
          int bh = bb * H_ + h;
          dst[(((size_t)bh * T_ + t) << 6) + e] = f2bf(acc[i][j][r]);
        }
      }
    }
  } else {
    for (int i = 0; i < 4; i++) {
      int row = m0 + wm * 64 + i * 16 + l15;
      int bb = row >> 11, t = row & 2047;
      for (int j = 0; j < 4; j++) {
        for (int r = 0; r < 4; r++) {
          int gcol = n0 + wn * 64 + j * 16 + quad * 4 + r;
          int h = gcol >> 6, e = gcol & 63;
          int bh = bb * H_ + h;
          vto[((size_t)(bh << 6) + e) * T_ + t] = f2bf(acc[i][j][r]);
        }
      }
    }
  }
}

// ---------------- flash attention v10 (proven ~55 us): 2-deep 32 KB LDS, 4/CU -------
// r13: direct-from-L2 V falsified (2.4x regression); LDS staging is the latency-hiding
// mechanism. Kept verbatim.
union AttnSmem {
  struct { ushort_t ks[2][64 * 64]; ushort_t vs[2][64 * 64]; } st;  // 32 KB
  struct { float ows[64 * 65]; float linv[64]; } ep;                // 16.9 KB
};

__global__ __launch_bounds__(256, 4) void k_attn(
    const ushort_t* __restrict__ q, const ushort_t* __restrict__ k,
    const ushort_t* __restrict__ vt, const float* __restrict__ wgt,
    float* __restrict__ out) {
  __shared__ __align__(16) AttnSmem sm;

  int id = blockIdx.x;      // 1024; bh fastest -> 4 heads/XCD (K+V L2-resident)
  int bh = id & 31, qt = id >> 5;   // qt in [0,32), 64 queries each
  int tid = threadIdx.x, wave = tid >> 6, lane = tid & 63;
  int l15 = lane & 15, quad = lane >> 4;

  s16x8 qf[2];              // 16 q-rows per wave
  {
    const ushort_t* qp =
        q + (((size_t)bh * T_ + qt * 64 + wave * 16 + l15) << 6) + quad * 8;
    qf[0] = *(const s16x8*)qp;
    qf[1] = *(const s16x8*)(qp + 32);
  }
  int hh = bh & 7;
  float wgl = wgt[hh * 64 + lane];

  f32x4 o[4];
  for (int j = 0; j < 4; j++) o[j] = (f32x4){0.f, 0.f, 0.f, 0.f};
  f32x4 lacc = (f32x4){0.f, 0.f, 0.f, 0.f};
  const s16x8 ones = {16256, 16256, 16256, 16256, 16256, 16256, 16256, 16256};  // bf16 1.0

  int srl = lane >> 3, sp = lane & 7;
  const ushort_t* kbase = k + ((size_t)bh * T_ << 6);
  const ushort_t* vbase = vt + ((size_t)bh << 6) * T_;
  const ushort_t* kptr[2];
  const ushort_t* vptr[2];
  for (int ii = 0; ii < 2; ii++) {
    int r = wave * 16 + ii * 8 + srl;
    int gkey = (r & 32) + (((r >> 2) & 3) << 3) + (((r >> 4) & 1) << 2) + (r & 3);
    kptr[ii] = kbase + ((size_t)gkey << 6) + ((sp ^ (r & 7)) << 3);
    int e = r;
    vptr[ii] = vbase + (size_t)e * T_ + ((sp ^ (e & 7)) << 3);
  }

#define STAGE(buf)                                                         \
  do {                                                                     \
    for (int ii = 0; ii < 2; ii++) {                                       \
      gl2lds16(kptr[ii], &sm.st.ks[buf][(wave * 16 + ii * 8) * 64]);       \
      gl2lds16(vptr[ii], &sm.st.vs[buf][(wave * 16 + ii * 8) * 64]);       \
      kptr[ii] += 64 * 64;                                                 \
      vptr[ii] += 64;                                                      \
    }                                                                      \
  } while (0)

  STAGE(0);                            // tile 0 (4 ops/wave)
  __builtin_amdgcn_s_waitcnt(0x0F70);  // vmcnt(0): tile 0 landed
  __builtin_amdgcn_s_barrier();
  __builtin_amdgcn_sched_barrier(0);

  for (int kt = 0; kt < 32; kt++) {
    // stage tile kt+1 into the other buffer; its readers ran in iter kt-1 (barrier'd)
    if (kt < 31) STAGE((kt + 1) & 1);
    const ushort_t* ksb = &sm.st.ks[0][0] + (kt & 1) * 4096;
    const ushort_t* vsb = &sm.st.vs[0][0] + (kt & 1) * 4096;

    __builtin_amdgcn_s_setprio(1);     // favor compute-phase waves (T5)
    s16x8 bfr[2];
    for (int c = 0; c < 2; c++) {
      f32x4 s0 = (f32x4){0.f, 0.f, 0.f, 0.f};
      f32x4 s1 = (f32x4){0.f, 0.f, 0.f, 0.f};
      for (int kc = 0; kc < 2; kc++) {
        int pc = (kc * 4 + quad) ^ (l15 & 7);
        s16x8 k0f = *(const s16x8*)&ksb[(c * 32 + l15) * 64 + pc * 8];
        s16x8 k1f = *(const s16x8*)&ksb[(c * 32 + 16 + l15) * 64 + pc * 8];
        s0 = __builtin_amdgcn_mfma_f32_16x16x32_bf16(k0f, qf[kc], s0, 0, 0, 0);
        s1 = __builtin_amdgcn_mfma_f32_16x16x32_bf16(k1f, qf[kc], s1, 0, 0, 0);
      }
      i32x4 d;
      d[0] = (int)pk2t(e2(s0[0]), e2(s0[1]));
      d[1] = (int)pk2t(e2(s0[2]), e2(s0[3]));
      d[2] = (int)pk2t(e2(s1[0]), e2(s1[1]));
      d[3] = (int)pk2t(e2(s1[2]), e2(s1[3]));
      bfr[c] = __builtin_bit_cast(s16x8, d);
    }

    for (int c = 0; c < 2; c++) {
      lacc = __builtin_amdgcn_mfma_f32_16x16x32_bf16(ones, bfr[c], lacc, 0, 0, 0);
      for (int et = 0; et < 4; et++) {
        int pc = (c * 4 + quad) ^ (l15 & 7);
        s16x8 vf = *(const s16x8*)&vsb[(et * 16 + l15) * 64 + pc * 8];
        o[et] = __builtin_amdgcn_mfma_f32_16x16x32_bf16(vf, bfr[c], o[et], 0, 0, 0);
      }
    }
    __builtin_amdgcn_s_setprio(0);

    // wait for tile kt+1 (issued before compute kt -> one full compute-phase in
    // flight, cheap wait); barrier so all reads of buf kt are done before iter
    // kt+1 stages into it.
    if (kt < 31) {
      __builtin_amdgcn_s_waitcnt(0x0F70);  // vmcnt(0)
      __builtin_amdgcn_s_barrier();
      __builtin_amdgcn_sched_barrier(0);
    }
  }
#undef STAGE

  int bb = bh >> 3;
  __syncthreads();   // all waves done reading ks/vs before ows overlays them
  {
    int row0 = wave * 16;
    if (quad == 0) sm.ep.linv[row0 + l15] = 1.f / lacc[0];
    for (int et = 0; et < 4; et++)
      for (int r = 0; r < 4; r++)
        sm.ep.ows[(row0 + l15) * 65 + et * 16 + quad * 4 + r] = o[et][r];
    // each wave reads back only its own 16 rows: no barrier needed
    for (int i = 0; i < 16; i++) {
      int row = row0 + i;
      int gt = qt * 64 + row;
      float val = sm.ep.ows[row * 65 + lane] * sm.ep.linv[row] * wgl;
      atomicAdd(&out[(((size_t)bb * T_ + gt) << 6) + lane], val);
    }
  }
}

extern "C" void kernel_launch(void* const* d_in, const int* in_sizes, int n_in,
                              void* d_out, int out_size, void* d_ws, size_t ws_size,
                              hipStream_t stream) {
  const float* obs = (const float*)d_in[0];
  const float* st  = (const float*)d_in[1];
  const float* Wq  = (const float*)d_in[2];
  const float* Wk  = (const float*)d_in[3];
  const float* Wv  = (const float*)d_in[4];
  const float* mw  = (const float*)d_in[5];

  const size_t WS_NEEDED = 27262976;   // proven 26 MB layout
  const size_t WS_BIG    = 44040192;   // +16 MB bf16 activations
  char* ws = (char*)d_ws;
  ushort_t* wt  = (ushort_t*)ws;                     // 1.5 MB
  float*    wgt = (float*)(ws + 1572864u);           // 2 KB
  ushort_t* qo  = (ushort_t*)(ws + 2097152u);        // [B,H,T,E] bf16, 8 MB
  ushort_t* ko  = (ushort_t*)(ws + 10485760u);       // [B,H,T,E] bf16, 8 MB
  ushort_t* vto = (ushort_t*)(ws + 18874368u);       // [B,H,E,T] bf16, 8 MB
  ushort_t* xo  = (ushort_t*)(ws + 27262976u);       // obs bf16, 8 MB
  ushort_t* xs  = (ushort_t*)(ws + 35651584u);       // st  bf16, 8 MB
  float*    out = (float*)d_out;

  hipMemsetAsync(d_out, 0, (size_t)out_size * sizeof(float), stream);
  if (ws_size < WS_NEEDED) return;

  int big = (ws_size >= WS_BIG);
  int preBlocks = big ? (193 + 4096) : 193;   // cvt section only with big workspace
  hipLaunchKernelGGL(k_pre, dim3(preBlocks), dim3(256), 0, stream,
                     Wq, Wk, Wv, mw, obs, st, wt, wgt, (unsigned*)xo, (unsigned*)xs);
  if (big) {
    hipLaunchKernelGGL(k_proj2, dim3(1536), dim3(256), 0, stream, xo, xs, wt, qo, ko, vto);
  } else {
    hipLaunchKernelGGL(k_proj,  dim3(768),  dim3(256), 0, stream, obs, st, wt, qo, ko, vto);
  }
  hipLaunchKernelGGL(k_attn, dim3(1024), dim3(256), 0, stream, qo, ko, vto, wgt, out);
}